// Round 20
// baseline (61.364 us; speedup 1.0000x reference)
//
#include <hip/hip_runtime.h>
#include <hip/hip_bf16.h>
#include <math.h>

#define BDIM 4096
#define DDIM 256
#define DB   128             // bytes per fp4 row (256 elems * 0.5B)
#define N2   8192
#define CSPLIT 32            // 32 col slices of 256
#define BROWS 512            // rows per block (8 waves x 64 rows)
#define BN 64                // cols per super-tile (8 KB = one stage quantum)
#define NT 4                 // super-tiles per block (256 cols)
#define TILEB (BN * DB)      // 8192 bytes per fp4 tile
#define RING 4
#define SCALE4 0x7B7B7B7B    // E8M0 123 = 2^-4 in every byte (fp4 stores x*16)

typedef float f32x4 __attribute__((ext_vector_type(4)));
typedef int   i32x4 __attribute__((ext_vector_type(4)));
typedef int   i32x8 __attribute__((ext_vector_type(8)));

#define WAITVM(N) asm volatile("s_waitcnt vmcnt(" #N ")" ::: "memory")

__device__ __forceinline__ void gload_lds16(const void* g, void* lds) {
    __builtin_amdgcn_global_load_lds(
        (const __attribute__((address_space(1))) unsigned int*)g,
        (__attribute__((address_space(3))) unsigned int*)lds, 16, 0, 0);
}

__device__ __forceinline__ i32x8 cat8(i32x4 lo, i32x4 hi) {
    return __builtin_shufflevector(lo, hi, 0, 1, 2, 3, 4, 5, 6, 7);
}

// encode one f32 (already normalized) to fp4 e2m1 code, value = code * 2^-4
__device__ __forceinline__ unsigned enc_fp4(float x) {
    float y = fabsf(x) * 16.0f;
    unsigned m = y < 0.25f ? 0u : y < 0.75f ? 1u : y < 1.25f ? 2u : y < 1.75f ? 3u
               : y < 2.5f  ? 4u : y < 3.5f  ? 5u : y < 5.0f  ? 6u : 7u;
    return m | (x < 0.0f ? 8u : 0u);
}

// ---------------- Kernel 1: L2-normalize rows, emit fp4 reps + fp32 positive dots ----------------
__global__ __launch_bounds__(256) void norm_kernel(const float* __restrict__ z1,
                                                   const float* __restrict__ z2,
                                                   unsigned char* __restrict__ reps4,
                                                   float* __restrict__ pos) {
    int gwave = (blockIdx.x * 256 + threadIdx.x) >> 6;
    int lane  = threadIdx.x & 63;
    if (gwave >= BDIM) return;

    const float4 a = *(const float4*)&z1[(size_t)gwave * DDIM + lane * 4];
    const float4 b = *(const float4*)&z2[(size_t)gwave * DDIM + lane * 4];

    float s1 = a.x*a.x + a.y*a.y + a.z*a.z + a.w*a.w;
    float s2 = b.x*b.x + b.y*b.y + b.z*b.z + b.w*b.w;
    float d  = a.x*b.x + a.y*b.y + a.z*b.z + a.w*b.w;
    #pragma unroll
    for (int off = 32; off; off >>= 1) {
        s1 += __shfl_xor(s1, off);
        s2 += __shfl_xor(s2, off);
        d  += __shfl_xor(d,  off);
    }
    float r1 = 1.0f / fmaxf(sqrtf(s1), 1e-12f);
    float r2 = 1.0f / fmaxf(sqrtf(s2), 1e-12f);

    unsigned w1 = enc_fp4(a.x * r1) | (enc_fp4(a.y * r1) << 4) |
                  (enc_fp4(a.z * r1) << 8) | (enc_fp4(a.w * r1) << 12);
    unsigned w2 = enc_fp4(b.x * r2) | (enc_fp4(b.y * r2) << 4) |
                  (enc_fp4(b.z * r2) << 8) | (enc_fp4(b.w * r2) << 12);

    *(unsigned short*)(reps4 + (size_t)gwave * DB + lane * 2)          = (unsigned short)w1;
    *(unsigned short*)(reps4 + (size_t)(gwave + BDIM) * DB + lane * 2) = (unsigned short)w2;

    if (lane == 0) pos[gwave] = d * r1 * r2;
}

// ---------------- Kernel 2: MX-fp4 GEMM + exp row sums, 64 rows/wave ----------------
// 512 blocks (16 rowgroups x 32 colslices) = 2/CU, 16 waves/CU. 8 waves x
// 64 rows: fp4 A-frags for 64 rows = only 32 VGPR (impossible in fp8 -- R10
// spilled), halving LDS-read bytes per output (4 -> 2 B/elem). Live set
// ~104 regs < LB(512,4)'s 128 cap. B: 8 KB super-tiles (64 cols), 4-buffer
// LDS ring, legal gload_lds (dest = tid*16), 8-granule XOR swizzle, counted
// vmcnt, raw barriers, raw v_exp_f32.
__global__ __launch_bounds__(512, 4) void lse18_kernel(const unsigned char* __restrict__ reps4,
                                                       float* __restrict__ partial) {
    __shared__ __attribute__((aligned(16))) unsigned char Bt[RING * TILEB];  // 32 KB

    const int tid  = threadIdx.x;
    const int wave = tid >> 6;
    const int lane = tid & 63;
    const int l15  = lane & 15;
    const int lq   = lane >> 4;
    const int rg   = blockIdx.x >> 5;
    const int cs   = blockIdx.x & 31;
    const int r0   = rg * BROWS;
    const int col0 = cs * (BN * NT);

    const i32x4 z4 = {0, 0, 0, 0};

    // hoist A fragments: 4 rowgroups x 2 K-halves, 16B/lane in low regs (32 VGPR)
    i32x8 afr[4][2];
    #pragma unroll
    for (int g = 0; g < 4; ++g) {
        const unsigned char* ap = reps4 + (size_t)(r0 + wave * 64 + g * 16 + l15) * DB + lq * 16;
        #pragma unroll
        for (int m = 0; m < 2; ++m)
            afr[g][m] = cat8(*(const i32x4*)(ap + m * 64), z4);
    }

    // per-lane B ds_read byte offsets: logical granule q = m*4+lq of col c
    // sits at physical granule q ^ (c&7); c&7 == l15&7
    int qo[2];
    #pragma unroll
    for (int m = 0; m < 2; ++m)
        qo[m] = (((m * 4 + lq) ^ (l15 & 7)) << 4);

    // stage source pointer: dest D = tid*16 (uniform + lane*16, legal);
    // physical granule pg of col tc holds logical granule pg ^ (tc&7)
    const unsigned char* sp;
    {
        int D  = tid * 16;
        int tc = D >> 7;                 // 128B per col
        int pg = (D >> 4) & 7;
        sp = reps4 + (size_t)(col0 + tc) * DB + ((pg ^ (tc & 7)) << 4);
    }

    f32x4 S[4] = {{0.f,0.f,0.f,0.f},{0.f,0.f,0.f,0.f},
                  {0.f,0.f,0.f,0.f},{0.f,0.f,0.f,0.f}};

    auto stage = [&](int buf) {
        gload_lds16(sp, &Bt[buf * TILEB + tid * 16]);
        sp += BN * DB;   // next super-tile (+8192 B)
    };

    auto compute = [&](int buf) {
        const unsigned char* bb = &Bt[buf * TILEB];
        #pragma unroll
        for (int fg = 0; fg < 4; ++fg) {
            const unsigned char* colp = bb + (fg * 16 + l15) * DB;
            f32x4 acc[4] = {{0.f,0.f,0.f,0.f},{0.f,0.f,0.f,0.f},
                            {0.f,0.f,0.f,0.f},{0.f,0.f,0.f,0.f}};
            __builtin_amdgcn_s_setprio(1);
            #pragma unroll
            for (int m = 0; m < 2; ++m) {
                i32x8 bv = cat8(*(const i32x4*)(colp + qo[m]), z4);
                #pragma unroll
                for (int g = 0; g < 4; ++g)
                    acc[g] = __builtin_amdgcn_mfma_scale_f32_16x16x128_f8f6f4(
                                 afr[g][m], bv, acc[g], 4, 4, 0, SCALE4, 0, SCALE4);
            }
            __builtin_amdgcn_s_setprio(0);
            #pragma unroll
            for (int g = 0; g < 4; ++g)
                #pragma unroll
                for (int r = 0; r < 4; ++r)
                    S[g][r] += __builtin_amdgcn_exp2f(fmaf(acc[g][r], 2.8853900817779268f, -2.8853900817779268f));
        }
    };

    // counted-vmcnt pipeline: RING=4, PD=2, 4 super-tiles, 1 load/thread/tile
    stage(0); stage(1);
    stage(2); WAITVM(2); __builtin_amdgcn_s_barrier(); compute(0);
    stage(3); WAITVM(2); __builtin_amdgcn_s_barrier(); compute(1);
    WAITVM(1); __builtin_amdgcn_s_barrier(); compute(2);
    WAITVM(0); __builtin_amdgcn_s_barrier(); compute(3);

    // reduce across the 16 column-lanes
    #pragma unroll
    for (int off = 1; off < 16; off <<= 1)
        #pragma unroll
        for (int g = 0; g < 4; ++g)
            #pragma unroll
            for (int r = 0; r < 4; ++r) S[g][r] += __shfl_xor(S[g][r], off);

    if (l15 == 0) {
        #pragma unroll
        for (int g = 0; g < 4; ++g)
            #pragma unroll
            for (int r = 0; r < 4; ++r)
                partial[(size_t)cs * N2 + r0 + wave * 64 + g * 16 + lq * 4 + r] = S[g][r];
    }
}

// ---------------- Kernel 3a: per-row sum of partials, log, per-block sums ----------------
__global__ __launch_bounds__(256) void finish1_kernel(const float* __restrict__ partial,
                                                      float* __restrict__ blocksum) {
    int row = blockIdx.x * 256 + threadIdx.x;
    float s = -1.0f;                     // remove diagonal self-term exp(0)~=1
    #pragma unroll
    for (int cc = 0; cc < CSPLIT; ++cc) s += partial[(size_t)cc * N2 + row];
    float v = logf(s);
    #pragma unroll
    for (int off = 32; off; off >>= 1) v += __shfl_xor(v, off);
    __shared__ float ws4[4];
    if ((threadIdx.x & 63) == 0) ws4[threadIdx.x >> 6] = v;
    __syncthreads();
    if (threadIdx.x == 0) blocksum[blockIdx.x] = ws4[0] + ws4[1] + ws4[2] + ws4[3];
}

// ---------------- Kernel 3b: final scalar ----------------
__global__ __launch_bounds__(256) void finish2_kernel(const float* __restrict__ blocksum,
                                                      const float* __restrict__ pos,
                                                      float* __restrict__ out) {
    float v = (threadIdx.x < 32) ? blocksum[threadIdx.x] : 0.f;
    float p = 0.f;
    for (int i = threadIdx.x; i < BDIM; i += 256) p += pos[i];
    float t = v - 4.0f * p;
    #pragma unroll
    for (int off = 32; off; off >>= 1) t += __shfl_xor(t, off);
    __shared__ float ws4[4];
    if ((threadIdx.x & 63) == 0) ws4[threadIdx.x >> 6] = t;
    __syncthreads();
    if (threadIdx.x == 0)
        out[0] = 2.0f + (ws4[0] + ws4[1] + ws4[2] + ws4[3]) / (float)N2;
}

extern "C" void kernel_launch(void* const* d_in, const int* in_sizes, int n_in,
                              void* d_out, int out_size, void* d_ws, size_t ws_size,
                              hipStream_t stream) {
    const float* z1 = (const float*)d_in[0];
    const float* z2 = (const float*)d_in[1];
    float* out = (float*)d_out;

    unsigned char* reps4 = (unsigned char*)d_ws;                       // 8192*128 = 1 MB
    float* partial  = (float*)((char*)d_ws + (size_t)N2 * DB);         // 32*8192*4 = 1 MB
    float* pos      = partial + (size_t)CSPLIT * N2;                   // 16 KB
    float* blocksum = pos + BDIM;                                      // 128 B

    norm_kernel<<<BDIM / 4, 256, 0, stream>>>(z1, z2, reps4, pos);
    lse18_kernel<<<(N2 / BROWS) * CSPLIT, 512, 0, stream>>>(reps4, partial);
    finish1_kernel<<<N2 / 256, 256, 0, stream>>>(partial, blocksum);
    finish2_kernel<<<1, 256, 0, stream>>>(blocksum, pos, out);
}

// Round 21
// 31.197 us; speedup vs baseline: 1.9670x; 1.9670x over previous
//
#include <hip/hip_runtime.h>
#include <hip/hip_bf16.h>
#include <math.h>

#define BDIM 4096
#define DDIM 256
#define DB   128             // bytes per fp4 row (256 elems * 0.5B)
#define N2   8192
#define CSPLIT 16            // 16 col slices of 512
#define BROWS 256            // rows per block (8 waves x 32 rows)
#define BN 128               // cols per super-tile (16 KB = 2 stage quanta)
#define NT 4                 // super-tiles per block (512 cols)
#define TILEB (BN * DB)      // 16384 bytes per fp4 tile
#define RING 4
#define SCALE4 0x7B7B7B7B    // E8M0 123 = 2^-4 in every byte (fp4 stores x*16)

typedef float f32x4 __attribute__((ext_vector_type(4)));
typedef int   i32x4 __attribute__((ext_vector_type(4)));
typedef int   i32x8 __attribute__((ext_vector_type(8)));

#define WAITVM(N) asm volatile("s_waitcnt vmcnt(" #N ")" ::: "memory")

__device__ __forceinline__ void gload_lds16(const void* g, void* lds) {
    __builtin_amdgcn_global_load_lds(
        (const __attribute__((address_space(1))) unsigned int*)g,
        (__attribute__((address_space(3))) unsigned int*)lds, 16, 0, 0);
}

__device__ __forceinline__ i32x8 cat8(i32x4 lo, i32x4 hi) {
    return __builtin_shufflevector(lo, hi, 0, 1, 2, 3, 4, 5, 6, 7);
}

// encode one f32 (already normalized) to fp4 e2m1 code, value = code * 2^-4
__device__ __forceinline__ unsigned enc_fp4(float x) {
    float y = fabsf(x) * 16.0f;
    unsigned m = y < 0.25f ? 0u : y < 0.75f ? 1u : y < 1.25f ? 2u : y < 1.75f ? 3u
               : y < 2.5f  ? 4u : y < 3.5f  ? 5u : y < 5.0f  ? 6u : 7u;
    return m | (x < 0.0f ? 8u : 0u);
}

// ---------------- Kernel 1: L2-normalize rows, emit fp4 reps + fp32 positive dots ----------------
__global__ __launch_bounds__(256) void norm_kernel(const float* __restrict__ z1,
                                                   const float* __restrict__ z2,
                                                   unsigned char* __restrict__ reps4,
                                                   float* __restrict__ pos) {
    int gwave = (blockIdx.x * 256 + threadIdx.x) >> 6;
    int lane  = threadIdx.x & 63;
    if (gwave >= BDIM) return;

    const float4 a = *(const float4*)&z1[(size_t)gwave * DDIM + lane * 4];
    const float4 b = *(const float4*)&z2[(size_t)gwave * DDIM + lane * 4];

    float s1 = a.x*a.x + a.y*a.y + a.z*a.z + a.w*a.w;
    float s2 = b.x*b.x + b.y*b.y + b.z*b.z + b.w*b.w;
    float d  = a.x*b.x + a.y*b.y + a.z*b.z + a.w*b.w;
    #pragma unroll
    for (int off = 32; off; off >>= 1) {
        s1 += __shfl_xor(s1, off);
        s2 += __shfl_xor(s2, off);
        d  += __shfl_xor(d,  off);
    }
    float r1 = 1.0f / fmaxf(sqrtf(s1), 1e-12f);
    float r2 = 1.0f / fmaxf(sqrtf(s2), 1e-12f);

    unsigned w1 = enc_fp4(a.x * r1) | (enc_fp4(a.y * r1) << 4) |
                  (enc_fp4(a.z * r1) << 8) | (enc_fp4(a.w * r1) << 12);
    unsigned w2 = enc_fp4(b.x * r2) | (enc_fp4(b.y * r2) << 4) |
                  (enc_fp4(b.z * r2) << 8) | (enc_fp4(b.w * r2) << 12);

    *(unsigned short*)(reps4 + (size_t)gwave * DB + lane * 2)          = (unsigned short)w1;
    *(unsigned short*)(reps4 + (size_t)(gwave + BDIM) * DB + lane * 2) = (unsigned short)w2;

    if (lane == 0) pos[gwave] = d * r1 * r2;
}

// ---------------- Kernel 2: MX-fp4 GEMM (K=128 scaled MFMA) + exp row sums ----------------
// R19 structure (best measured) with halved barrier count: 512 blocks
// (32 rowgroups x 16 colslices) = 2/CU, 8 waves x 32 rows, 64-VGPR class.
// B: 16 KB super-tiles (128 cols) staged as TWO legal gload_lds per thread
// (each dest = uniform + lane*16), quad-buffer with NO reuse (4 bufs, 4
// tiles), 8-granule XOR swizzle, counted vmcnt, 4 barriers total/block.
__global__ __launch_bounds__(512, 4) void lse19_kernel(const unsigned char* __restrict__ reps4,
                                                       float* __restrict__ partial) {
    __shared__ __attribute__((aligned(16))) unsigned char Bt[RING * TILEB];  // 64 KB

    const int tid  = threadIdx.x;
    const int wave = tid >> 6;
    const int lane = tid & 63;
    const int l15  = lane & 15;
    const int lq   = lane >> 4;
    const int rg   = blockIdx.x >> 4;
    const int cs   = blockIdx.x & 15;
    const int r0   = rg * BROWS;
    const int col0 = cs * (BN * NT);

    const i32x4 z4 = {0, 0, 0, 0};

    // hoist A fragments: 2 rowgroups x 2 K-halves, 16B/lane in low regs
    i32x8 afr0[2], afr1[2];
    {
        const unsigned char* a0 = reps4 + (size_t)(r0 + wave * 32 + l15) * DB + lq * 16;
        const unsigned char* a1 = a0 + 16 * DB;
        #pragma unroll
        for (int m = 0; m < 2; ++m) {
            afr0[m] = cat8(*(const i32x4*)(a0 + m * 64), z4);
            afr1[m] = cat8(*(const i32x4*)(a1 + m * 64), z4);
        }
    }

    // per-lane B ds_read byte offsets: logical granule q = m*4+lq of col c
    // sits at physical granule q ^ (c&7); c&7 == l15&7 (fg*16 = 0 mod 8)
    int qo[2];
    #pragma unroll
    for (int m = 0; m < 2; ++m)
        qo[m] = (((m * 4 + lq) ^ (l15 & 7)) << 4);

    // stage source pointers for the two 8KB halves of a 16KB super-tile:
    // dest D = half*8192 + tid*16 (each = uniform + lane*16, legal);
    // physical granule pg of col tc holds logical granule pg ^ (tc&7)
    const unsigned char* sp[2];
    #pragma unroll
    for (int h = 0; h < 2; ++h) {
        int D  = h * 8192 + tid * 16;
        int tc = D >> 7;                 // 128B per col
        int pg = (D >> 4) & 7;
        sp[h] = reps4 + (size_t)(col0 + tc) * DB + ((pg ^ (tc & 7)) << 4);
    }

    f32x4 S0 = {0.f,0.f,0.f,0.f}, S1 = {0.f,0.f,0.f,0.f};

    auto stage = [&](int buf) {
        #pragma unroll
        for (int h = 0; h < 2; ++h) {
            gload_lds16(sp[h], &Bt[buf * TILEB + h * 8192 + tid * 16]);
            sp[h] += BN * DB;   // next super-tile (+16384 B)
        }
    };

    auto compute = [&](int buf) {
        const unsigned char* bb = &Bt[buf * TILEB];
        #pragma unroll
        for (int fg = 0; fg < 8; ++fg) {
            const unsigned char* colp = bb + (fg * 16 + l15) * DB;
            f32x4 acc0 = {0.f,0.f,0.f,0.f}, acc1 = {0.f,0.f,0.f,0.f};
            __builtin_amdgcn_s_setprio(1);
            #pragma unroll
            for (int m = 0; m < 2; ++m) {
                i32x8 bv = cat8(*(const i32x4*)(colp + qo[m]), z4);
                acc0 = __builtin_amdgcn_mfma_scale_f32_16x16x128_f8f6f4(
                           afr0[m], bv, acc0, 4, 4, 0, SCALE4, 0, SCALE4);
                acc1 = __builtin_amdgcn_mfma_scale_f32_16x16x128_f8f6f4(
                           afr1[m], bv, acc1, 4, 4, 0, SCALE4, 0, SCALE4);
            }
            __builtin_amdgcn_s_setprio(0);
            #pragma unroll
            for (int r = 0; r < 4; ++r) {
                S0[r] += __builtin_amdgcn_exp2f(fmaf(acc0[r], 2.8853900817779268f, -2.8853900817779268f));
                S1[r] += __builtin_amdgcn_exp2f(fmaf(acc1[r], 2.8853900817779268f, -2.8853900817779268f));
            }
        }
    };

    // fully-peeled quad-buffer pipeline (no buffer reuse), 2 loads/stage
    stage(0); stage(1);
    stage(2); WAITVM(4); __builtin_amdgcn_s_barrier(); compute(0);
    stage(3); WAITVM(4); __builtin_amdgcn_s_barrier(); compute(1);
    WAITVM(2); __builtin_amdgcn_s_barrier(); compute(2);
    WAITVM(0); __builtin_amdgcn_s_barrier(); compute(3);

    // reduce across the 16 column-lanes
    #pragma unroll
    for (int off = 1; off < 16; off <<= 1) {
        #pragma unroll
        for (int r = 0; r < 4; ++r) {
            S0[r] += __shfl_xor(S0[r], off);
            S1[r] += __shfl_xor(S1[r], off);
        }
    }

    if (l15 == 0) {
        #pragma unroll
        for (int r = 0; r < 4; ++r) {
            partial[(size_t)cs * N2 + r0 + wave * 32 + lq * 4 + r]      = S0[r];
            partial[(size_t)cs * N2 + r0 + wave * 32 + 16 + lq * 4 + r] = S1[r];
        }
    }
}

// ---------------- Kernel 3a: per-row sum of partials, log, per-block sums ----------------
__global__ __launch_bounds__(256) void finish1_kernel(const float* __restrict__ partial,
                                                      float* __restrict__ blocksum) {
    int row = blockIdx.x * 256 + threadIdx.x;
    float s = -1.0f;                     // remove diagonal self-term exp(0)~=1
    #pragma unroll
    for (int cc = 0; cc < CSPLIT; ++cc) s += partial[(size_t)cc * N2 + row];
    float v = logf(s);
    #pragma unroll
    for (int off = 32; off; off >>= 1) v += __shfl_xor(v, off);
    __shared__ float ws4[4];
    if ((threadIdx.x & 63) == 0) ws4[threadIdx.x >> 6] = v;
    __syncthreads();
    if (threadIdx.x == 0) blocksum[blockIdx.x] = ws4[0] + ws4[1] + ws4[2] + ws4[3];
}

// ---------------- Kernel 3b: final scalar ----------------
__global__ __launch_bounds__(256) void finish2_kernel(const float* __restrict__ blocksum,
                                                      const float* __restrict__ pos,
                                                      float* __restrict__ out) {
    float v = (threadIdx.x < 32) ? blocksum[threadIdx.x] : 0.f;
    float p = 0.f;
    for (int i = threadIdx.x; i < BDIM; i += 256) p += pos[i];
    float t = v - 4.0f * p;
    #pragma unroll
    for (int off = 32; off; off >>= 1) t += __shfl_xor(t, off);
    __shared__ float ws4[4];
    if ((threadIdx.x & 63) == 0) ws4[threadIdx.x >> 6] = t;
    __syncthreads();
    if (threadIdx.x == 0)
        out[0] = 2.0f + (ws4[0] + ws4[1] + ws4[2] + ws4[3]) / (float)N2;
}

extern "C" void kernel_launch(void* const* d_in, const int* in_sizes, int n_in,
                              void* d_out, int out_size, void* d_ws, size_t ws_size,
                              hipStream_t stream) {
    const float* z1 = (const float*)d_in[0];
    const float* z2 = (const float*)d_in[1];
    float* out = (float*)d_out;

    unsigned char* reps4 = (unsigned char*)d_ws;                       // 8192*128 = 1 MB
    float* partial  = (float*)((char*)d_ws + (size_t)N2 * DB);         // 16*8192*4 = 512 KB
    float* pos      = partial + (size_t)CSPLIT * N2;                   // 16 KB
    float* blocksum = pos + BDIM;                                      // 128 B

    norm_kernel<<<BDIM / 4, 256, 0, stream>>>(z1, z2, reps4, pos);
    lse19_kernel<<<(N2 / BROWS) * CSPLIT, 512, 0, stream>>>(reps4, partial);
    finish1_kernel<<<N2 / 256, 256, 0, stream>>>(partial, blocksum);
    finish2_kernel<<<1, 256, 0, stream>>>(blocksum, pos, out);
}